// Round 2
// baseline (216.437 us; speedup 1.0000x reference)
//
#include <hip/hip_runtime.h>

#define LAMBDA_COORD 5.0f
#define LAMBDA_NOOBJ 0.5f
#define DD 30
#define BLOCK 64                      // one wave per block: no cross-wave barrier coupling
#define CELLS 64                      // cells per chunk
#define ITERS 4                       // chunks per block -> 3136 blocks (atomic count == round 1)
#define F4_PER_CHUNK (CELLS * DD / 4) // 480 float4 per input per chunk

typedef const __attribute__((address_space(1))) void* gas_ptr;
typedef __attribute__((address_space(3))) void* las_ptr;

// async global->LDS, 16B/lane; LDS dest = wave-uniform base + lane*16 (matches our linear order)
__device__ __forceinline__ void glds16(const float4* g, void* l) {
    __builtin_amdgcn_global_load_lds((gas_ptr)g, (las_ptr)l, 16, 0, 0);
}

__device__ __forceinline__ float iou_t(float tx, float ty, float tw, float th,
                                       float px, float py, float pw, float ph) {
    float xl = fmaxf(tx - tw * 0.5f, px - pw * 0.5f);
    float yt = fmaxf(ty - th * 0.5f, py - ph * 0.5f);
    float xr = fminf(tx + tw * 0.5f, px + pw * 0.5f);
    float yb = fminf(ty + th * 0.5f, py + ph * 0.5f);
    bool valid = (xr >= xl) && (yb >= yt);
    float inter = (xr - xl) * (yb - yt);
    float uni = tw * th + pw * ph - inter;
    float safe = (uni == 0.0f) ? 1.0f : uni;
    return valid ? (inter / safe) : 0.0f;
}

__global__ __launch_bounds__(BLOCK) void yolo_loss_kernel(
    const float* __restrict__ pred, const float* __restrict__ targ,
    float* __restrict__ out) {
    // 2 * 64*30*4 = 15360 B LDS -> 10 blocks/CU (LDS-limited), 10 independent waves
    __shared__ __align__(16) float sp[CELLS * DD];
    __shared__ __align__(16) float st[CELLS * DD];

    const int tid = threadIdx.x;
    float acc = 0.0f;

    for (int it = 0; it < ITERS; ++it) {
        const size_t chunk = (size_t)blockIdx.x * ITERS + it;
        const float4* gp = (const float4*)pred + chunk * F4_PER_CHUNK;
        const float4* gt = (const float4*)targ + chunk * F4_PER_CHUNK;

        __syncthreads(); // WAR guard on LDS reuse (1 wave: compiles to waitcnt, trivial)

#pragma unroll
        for (int j = 0; j < 7; ++j) {
            glds16(gp + j * 64 + tid, (char*)sp + j * 1024);
            glds16(gt + j * 64 + tid, (char*)st + j * 1024);
        }
        if (tid < 32) { // tail: 480 = 7*64 + 32
            glds16(gp + 448 + tid, (char*)sp + 7 * 1024);
            glds16(gt + 448 + tid, (char*)st + 7 * 1024);
        }
        __syncthreads(); // drains vmcnt -> LDS staging visible

        const float* p = &sp[tid * DD];
        const float* t = &st[tid * DD];

        float t4 = t[4];
        float obj = (t4 > 0.0f) ? 1.0f : 0.0f;
        float noobj = (t4 == 0.0f) ? 1.0f : 0.0f;

        float cls = 0.0f;
#pragma unroll
        for (int k = 10; k < 30; ++k) {
            float d = t[k] - p[k];
            cls += d * d;
        }
        cls *= obj;

        float d4 = t4 - p[4];
        float conf_noobj = noobj * d4 * d4;

        float tx = t[0], ty = t[1], tw = t[2], th = t[3];
        float iou1 = iou_t(tx, ty, tw, th, p[0], p[1], p[2], p[3]);
        float iou2 = iou_t(tx, ty, tw, th, p[5], p[6], p[7], p[8]);
        float resp1 = (iou1 > iou2) ? 1.0f : 0.0f;
        float m1 = obj * resp1;
        float m2 = obj * (1.0f - resp1);

        float e1 = iou1 - p[4];
        float e2 = iou2 - p[9];
        float conf_obj = m1 * e1 * e1 + m2 * e2 * e2;

        float dx1 = tx - p[0], dy1 = ty - p[1];
        float dx2 = tx - p[5], dy2 = ty - p[6];
        float xy = m1 * (dx1 * dx1 + dy1 * dy1) + m2 * (dx2 * dx2 + dy2 * dy2);

        float dw1 = tw - p[2], dh1 = th - p[3];
        float dw2 = tw - p[7], dh2 = th - p[8];
        float wh = m1 * (dw1 * dw1 + dh1 * dh1) + m2 * (dw2 * dw2 + dh2 * dh2);

        acc += LAMBDA_COORD * (xy + wh) + conf_obj + LAMBDA_NOOBJ * conf_noobj + cls;
    }

    // 64-lane wave reduction
#pragma unroll
    for (int off = 32; off > 0; off >>= 1) acc += __shfl_down(acc, off);
    if (tid == 0) atomicAdd(out, acc * (1.0f / 16384.0f));
}

extern "C" void kernel_launch(void* const* d_in, const int* in_sizes, int n_in,
                              void* d_out, int out_size, void* d_ws, size_t ws_size,
                              hipStream_t stream) {
    const float* pred = (const float*)d_in[0];  // y
    const float* targ = (const float*)d_in[1];  // gt
    float* out = (float*)d_out;

    hipMemsetAsync(out, 0, sizeof(float), stream);

    const int cells = in_sizes[0] / DD;          // 802816
    const int grid = cells / (CELLS * ITERS);    // 3136 (exact)
    yolo_loss_kernel<<<grid, BLOCK, 0, stream>>>(pred, targ, out);
}